// Round 2
// baseline (197.207 us; speedup 1.0000x reference)
//
#include <hip/hip_runtime.h>

// Embedding gather: out[b,s,:] = weight[token_ids[b,s],:]
// BATCH=4, SEQ=4096, DIM=1024, VOCAB=32000, fp32.
// HBM budget: 64 MiB sequential writes + ~50 MiB unique random 4KiB row
// reads (~114 MiB) -> ~20 us at mixed-stream BW. Kernel-local now ~32 us.
//
// This version: 4 tokens per wave (was 2).
//  - ONE int4 load fetches all 4 wave-uniform token ids (one round trip,
//    was 2 scalar loads) -> half the dependent id-latency events.
//  - 16 independent 16B row loads in flight before any dependent store;
//    4096 waves instead of 8192 -> half the wave churn, same aggregate
//    outstanding-load capacity (16 waves/CU x 16 loads = 256/CU).
//  - nt stores retained: output is write-once, keep it out of L2 so
//    duplicate token rows (~22% of reads) stay L2/L3-resident.

#define DIM 1024
#define F4_PER_ROW (DIM / 4)          // 256 float4 per row
#define TOKENS_PER_WAVE 4
#define WAVES_PER_BLOCK 4             // 256 threads
#define TOKENS_PER_BLOCK (TOKENS_PER_WAVE * WAVES_PER_BLOCK)  // 16

typedef float f32x4 __attribute__((ext_vector_type(4)));
typedef int   i32x4 __attribute__((ext_vector_type(4)));

__global__ __launch_bounds__(256) void embedding_gather_kernel(
    const int* __restrict__ token_ids,
    const f32x4* __restrict__ weight,   // [VOCAB, DIM/4]
    f32x4* __restrict__ out,            // [N_TOKENS, DIM/4]
    int n_tokens)
{
    const int wave = threadIdx.x >> 6;        // 0..3
    const int lane = threadIdx.x & 63;        // 0..63
    const int t0 = (blockIdx.x * WAVES_PER_BLOCK + wave) * TOKENS_PER_WAVE;
    if (t0 >= n_tokens) return;

    // All 4 wave-uniform token ids in one 16B load (t0 is a multiple of 4,
    // so token_ids + t0 is 16B-aligned).
    const i32x4 ids = *reinterpret_cast<const i32x4*>(token_ids + t0);

    const f32x4* __restrict__ srcA = weight + (size_t)ids.x * F4_PER_ROW;
    const f32x4* __restrict__ srcB = weight + (size_t)ids.y * F4_PER_ROW;
    const f32x4* __restrict__ srcC = weight + (size_t)ids.z * F4_PER_ROW;
    const f32x4* __restrict__ srcD = weight + (size_t)ids.w * F4_PER_ROW;
    f32x4* __restrict__ dstA = out + (size_t)t0 * F4_PER_ROW;
    f32x4* __restrict__ dstB = dstA + F4_PER_ROW;
    f32x4* __restrict__ dstC = dstB + F4_PER_ROW;
    f32x4* __restrict__ dstD = dstC + F4_PER_ROW;

    // 16 independent coalesced 1 KiB/wave loads, all issued before any
    // dependent store (compiler staggers vmcnt waits per store).
    f32x4 a0 = srcA[lane];
    f32x4 a1 = srcA[lane + 64];
    f32x4 a2 = srcA[lane + 128];
    f32x4 a3 = srcA[lane + 192];
    f32x4 b0 = srcB[lane];
    f32x4 b1 = srcB[lane + 64];
    f32x4 b2 = srcB[lane + 128];
    f32x4 b3 = srcB[lane + 192];
    f32x4 c0 = srcC[lane];
    f32x4 c1 = srcC[lane + 64];
    f32x4 c2 = srcC[lane + 128];
    f32x4 c3 = srcC[lane + 192];
    f32x4 d0 = srcD[lane];
    f32x4 d1 = srcD[lane + 64];
    f32x4 d2 = srcD[lane + 128];
    f32x4 d3 = srcD[lane + 192];

    // Streaming (nt) stores: bypass L2 allocation for the write-once output.
    __builtin_nontemporal_store(a0, &dstA[lane]);
    __builtin_nontemporal_store(a1, &dstA[lane + 64]);
    __builtin_nontemporal_store(a2, &dstA[lane + 128]);
    __builtin_nontemporal_store(a3, &dstA[lane + 192]);
    __builtin_nontemporal_store(b0, &dstB[lane]);
    __builtin_nontemporal_store(b1, &dstB[lane + 64]);
    __builtin_nontemporal_store(b2, &dstB[lane + 128]);
    __builtin_nontemporal_store(b3, &dstB[lane + 192]);
    __builtin_nontemporal_store(c0, &dstC[lane]);
    __builtin_nontemporal_store(c1, &dstC[lane + 64]);
    __builtin_nontemporal_store(c2, &dstC[lane + 128]);
    __builtin_nontemporal_store(c3, &dstC[lane + 192]);
    __builtin_nontemporal_store(d0, &dstD[lane]);
    __builtin_nontemporal_store(d1, &dstD[lane + 64]);
    __builtin_nontemporal_store(d2, &dstD[lane + 128]);
    __builtin_nontemporal_store(d3, &dstD[lane + 192]);
}

extern "C" void kernel_launch(void* const* d_in, const int* in_sizes, int n_in,
                              void* d_out, int out_size, void* d_ws, size_t ws_size,
                              hipStream_t stream) {
    const int* token_ids = (const int*)d_in[0];       // [4, 4096] int32
    const f32x4* weight = (const f32x4*)d_in[1];      // [32000, 1024] f32
    f32x4* out = (f32x4*)d_out;                       // [4, 4096, 1024] f32

    const int n_tokens = in_sizes[0];                 // 16384
    dim3 grid((n_tokens + TOKENS_PER_BLOCK - 1) / TOKENS_PER_BLOCK);
    dim3 block(WAVES_PER_BLOCK * 64);
    embedding_gather_kernel<<<grid, block, 0, stream>>>(token_ids, weight, out, n_tokens);
}

// Round 3
// 196.763 us; speedup vs baseline: 1.0023x; 1.0023x over previous
//
#include <hip/hip_runtime.h>

// Embedding gather: out[b,s,:] = weight[token_ids[b,s],:]
// BATCH=4, SEQ=4096, DIM=1024, VOCAB=32000, fp32.
// Mandatory HBM traffic: 64 MiB streaming writes + ~51 MiB unique random
// 4 KiB row reads (~115 MiB) -> ~20 us at copy BW, ~26-30 us at realistic
// mixed gather/stream efficiency. Harness re-poison fills (~163 us) dominate
// dur_us and are not kernel-controllable.
//
// Best measured config (round 1, 196.1 us): 2 tokens/wave, 2048 blocks
//  = 8192 waves = 32 waves/CU (FULL occupancy). Round 2 (4 tok/wave,
//  half occupancy) regressed: TLP matters more than per-wave ILP here.
//  - int2 id load: both wave-uniform token ids in one 8 B round trip.
//  - 8 independent 1 KiB/wave row loads in flight before any store.
//  - nt stores: output is write-once; bypass L2 allocation so duplicate
//    token rows (~22% of reads) stay cache-resident.

#define DIM 1024
#define F4_PER_ROW (DIM / 4)          // 256 float4 per row
#define TOKENS_PER_WAVE 2
#define WAVES_PER_BLOCK 4             // 256 threads
#define TOKENS_PER_BLOCK (TOKENS_PER_WAVE * WAVES_PER_BLOCK)  // 8

typedef float f32x4 __attribute__((ext_vector_type(4)));
typedef int   i32x2 __attribute__((ext_vector_type(2)));

__global__ __launch_bounds__(256) void embedding_gather_kernel(
    const int* __restrict__ token_ids,
    const f32x4* __restrict__ weight,   // [VOCAB, DIM/4]
    f32x4* __restrict__ out,            // [N_TOKENS, DIM/4]
    int n_tokens)
{
    const int wave = threadIdx.x >> 6;        // 0..3
    const int lane = threadIdx.x & 63;        // 0..63
    const int t0 = (blockIdx.x * WAVES_PER_BLOCK + wave) * TOKENS_PER_WAVE;
    if (t0 >= n_tokens) return;

    // Both wave-uniform token ids in one 8 B load (t0 is even -> aligned).
    const i32x2 ids = *reinterpret_cast<const i32x2*>(token_ids + t0);

    const f32x4* __restrict__ srcA = weight + (size_t)ids.x * F4_PER_ROW;
    const f32x4* __restrict__ srcB = weight + (size_t)ids.y * F4_PER_ROW;
    f32x4* __restrict__ dstA = out + (size_t)t0 * F4_PER_ROW;
    f32x4* __restrict__ dstB = dstA + F4_PER_ROW;

    // 8 independent coalesced 1 KiB/wave loads, all issued before any
    // dependent store (compiler staggers vmcnt waits per store).
    f32x4 a0 = srcA[lane];
    f32x4 a1 = srcA[lane + 64];
    f32x4 a2 = srcA[lane + 128];
    f32x4 a3 = srcA[lane + 192];
    f32x4 b0 = srcB[lane];
    f32x4 b1 = srcB[lane + 64];
    f32x4 b2 = srcB[lane + 128];
    f32x4 b3 = srcB[lane + 192];

    // Streaming (nt) stores: bypass L2 allocation for the write-once output.
    __builtin_nontemporal_store(a0, &dstA[lane]);
    __builtin_nontemporal_store(a1, &dstA[lane + 64]);
    __builtin_nontemporal_store(a2, &dstA[lane + 128]);
    __builtin_nontemporal_store(a3, &dstA[lane + 192]);
    __builtin_nontemporal_store(b0, &dstB[lane]);
    __builtin_nontemporal_store(b1, &dstB[lane + 64]);
    __builtin_nontemporal_store(b2, &dstB[lane + 128]);
    __builtin_nontemporal_store(b3, &dstB[lane + 192]);
}

extern "C" void kernel_launch(void* const* d_in, const int* in_sizes, int n_in,
                              void* d_out, int out_size, void* d_ws, size_t ws_size,
                              hipStream_t stream) {
    const int* token_ids = (const int*)d_in[0];       // [4, 4096] int32
    const f32x4* weight = (const f32x4*)d_in[1];      // [32000, 1024] f32
    f32x4* out = (f32x4*)d_out;                       // [4, 4096, 1024] f32

    const int n_tokens = in_sizes[0];                 // 16384
    dim3 grid((n_tokens + TOKENS_PER_BLOCK - 1) / TOKENS_PER_BLOCK);
    dim3 block(WAVES_PER_BLOCK * 64);
    embedding_gather_kernel<<<grid, block, 0, stream>>>(token_ids, weight, out, n_tokens);
}